// Round 5
// baseline (391.270 us; speedup 1.0000x reference)
//
#include <hip/hip_runtime.h>
#include <hip/hip_bf16.h>

typedef unsigned short u16;
typedef unsigned long long u64;
typedef short bf16x8 __attribute__((ext_vector_type(8)));
typedef float f32x4 __attribute__((ext_vector_type(4)));

#define EQ_SCALE   0.04419417382415922f     /* 1/sqrt(512) */
#define CONV_SCALE 0.014731391274719738f    /* 1/sqrt(512*9) */

// workspace layout (bytes)
#define WS_S   0                                  // f32 [8][512]
#define WS_ESC (16*1024)                          // f32 [8][512]  = conv_scale*demod
#define WS_WSQ (32*1024)                          // f32 [512][512]
#define WS_WT  (32*1024 + 1024*1024)              // bf16 [9][512][512]  (khw, o, ci)
#define WS_XS  (WS_WT + 9*512*512*2)              // bf16 [8][64][64][512] (b, y, x, ci)
#define WS_Z   (WS_XS + 8*64*64*512*2)            // bf16 zero page, 64 KB (contiguous after xs)

__device__ __forceinline__ void gld16(void* l, const void* g) {
  __builtin_amdgcn_global_load_lds((const __attribute__((address_space(1))) void*)g,
                                   (__attribute__((address_space(3))) void*)l,
                                   16, 0, 0);
}

// round-to-nearest-even f32 -> bf16 bits
__device__ __forceinline__ u16 f2b_rne(float f) {
  union { float f; unsigned int i; } c; c.f = f;
  unsigned int r = (c.i + 0x7FFFu + ((c.i >> 16) & 1u)) >> 16;
  return (u16)r;
}

// fused prep 1: zero page (32 blocks) + wsq (1024 blocks) + style (1024 blocks)
__global__ void __launch_bounds__(256) k_pre1(
    const float* __restrict__ style, const float* __restrict__ mw,
    const float* __restrict__ mb, const float* __restrict__ w,
    float* __restrict__ s, float* __restrict__ wsq, u64* __restrict__ z) {
  int bid = blockIdx.x, t = threadIdx.x;
  if (bid < 32) { z[bid * 256 + t] = 0ull; return; }
  if (bid < 1056) {                              // wsq[o][i] = sum_khw w[o][i][khw]^2
    int idx = (bid - 32) * 256 + t;
    const float* p = w + idx * 9;
    float a = 0.f;
#pragma unroll
    for (int k = 0; k < 9; ++k) { float v = p[k]; a += v * v; }
    wsq[idx] = a;
    return;
  }
  // style: one wave per output, s[b][i] = eq_scale*dot(style[b], mw[i]) + mb[i]
  int g = (bid - 1056) * 4 + (t >> 6);           // 4096
  int lane = t & 63;
  int b = g >> 9, i = g & 511;
  const float4* sr = (const float4*)(style + (b << 9));
  const float4* wr = (const float4*)(mw + (i << 9));
  float acc = 0.f;
#pragma unroll
  for (int j = 0; j < 2; ++j) {
    float4 a4 = sr[lane * 2 + j];
    float4 w4 = wr[lane * 2 + j];
    acc += a4.x * w4.x + a4.y * w4.y + a4.z * w4.z + a4.w * w4.w;
  }
#pragma unroll
  for (int off = 32; off; off >>= 1) acc += __shfl_xor(acc, off);
  if (lane == 0) s[g] = acc * EQ_SCALE + mb[i];
}

// fused prep 2: esc (1024) + wt relayout (1024) + xs transpose/scale (4096)
__global__ void __launch_bounds__(256) k_pre2(
    const float* __restrict__ wsq, const float* __restrict__ s,
    const float* __restrict__ w, const float* __restrict__ x,
    float* __restrict__ esc, u16* __restrict__ wt, u16* __restrict__ xs) {
  __shared__ u16 tile[64 * 66];
  int bid = blockIdx.x, t = threadIdx.x;
  if (bid < 1024) {                              // esc, one wave per output
    int g = bid * 4 + (t >> 6);
    int lane = t & 63;
    int b = g >> 9, o = g & 511;
    const float4* wr = (const float4*)(wsq + (o << 9));
    const float4* sr = (const float4*)(s + (b << 9));
    float a = 0.f;
#pragma unroll
    for (int j = 0; j < 2; ++j) {
      float4 wv = wr[lane * 2 + j];
      float4 sv = sr[lane * 2 + j];
      a += wv.x*sv.x*sv.x + wv.y*sv.y*sv.y + wv.z*sv.z*sv.z + wv.w*sv.w*sv.w;
    }
#pragma unroll
    for (int off = 32; off; off >>= 1) a += __shfl_xor(a, off);
    if (lane == 0) esc[g] = CONV_SCALE * rsqrtf(CONV_SCALE * CONV_SCALE * a + 1e-8f);
    return;
  }
  if (bid < 2048) {                              // wt[khw][o][i] = bf16(w[o][i][khw])
    int idx = (bid - 1024) * 256 + t;
    const float* p = w + idx * 9;
#pragma unroll
    for (int k = 0; k < 9; ++k) wt[k * 262144 + idx] = f2b_rne(p[k]);
    return;
  }
  // xs[b][y][x][i] = bf16(x[b][i][y][x] * s[b][i])
  int v = bid - 2048;                            // 0..4095
  int by = v & 511, i0 = (v >> 9) << 6;
  int b = by >> 6, y = by & 63;
  int wv = t >> 6, lane = t & 63;
  for (int k = 0; k < 16; ++k) {
    int il = wv + (k << 2);
    int i = i0 + il;
    float val = x[((((b << 9) + i) << 6) | y) << 6 | lane] * s[(b << 9) + i];
    tile[lane * 66 + il] = f2b_rne(val);
  }
  __syncthreads();
  // vectorized store: thread = (row=t>>4, qt=t&15); 4 iters of short4
  int row = t >> 4, qt = t & 15;
  for (int k = 0; k < 4; ++k) {
    int xc = row + k * 16;
    short4 o4;
    o4.x = (short)tile[xc * 66 + qt * 4 + 0];
    o4.y = (short)tile[xc * 66 + qt * 4 + 1];
    o4.z = (short)tile[xc * 66 + qt * 4 + 2];
    o4.w = (short)tile[xc * 66 + qt * 4 + 3];
    *(short4*)(&xs[((((b << 6) | y) << 6 | xc) << 9) + i0 + qt * 4]) = o4;
  }
}

// Conv: implicit GEMM. Block tile 256(o) x 256(4 rows x 64 cols), 1024 threads,
// 16 waves = 4(o-group) x 4(row), wave tile 64x64 (acc=64 VGPR, no spill).
// Per tap: 2 phases of {8 ds_read_b128 + stage-issue -> s_barrier -> setprio
// 16-MFMA cluster}; counted vmcnt at tap boundary only. A+B LDS = 160 KB,
// grid 256 = 1 block/CU, one round.
__global__ void __launch_bounds__(1024) k_conv(
    const u16* __restrict__ wt, const u16* __restrict__ xs,
    const float* __restrict__ esc, const float* __restrict__ noise,
    const float* __restrict__ nwp, const float* __restrict__ abias,
    float* __restrict__ out) {
  __shared__ __align__(16) u16 ldsA[2][256 * 64];   // 2 x 32 KB, xor-swizzled chunks
  __shared__ __align__(16) u16 ldsB[2][384 * 64];   // 2 x 48 KB: 6 input rows x 64 cols

  const int t = threadIdx.x;
  const int w = t >> 6, lane = t & 63;
  const int og = w >> 2, wrw = w & 3;           // 4(o-group of 64) x 4(row) wave grid
  const int quad = lane >> 4, l15 = lane & 15;

  // XCD pinning: xcds 0-3 own o-half 0, xcds 4-7 own o-half 1 (2.25 MB wt/half).
  const int flat = blockIdx.y * 2 + blockIdx.x;   // 0..255
  const int xcd = flat & 7, rest = flat >> 3;     // 8 x 32
  const int o0 = (xcd >> 2) << 8;                 // 0 or 256
  const int nt = (rest << 2) | (xcd & 3);         // 0..127, bijective
  const int b = nt >> 4, y0 = (nt & 15) << 2;     // 4 output rows per tile

  // B staging source offsets into xs (zero page is contiguous after xs).
  // chunk j covers LDS rows via c = j*1024 + t; 3 chunks/thread cover 384 pos.
  int bgOff[3];
#pragma unroll
  for (int j = 0; j < 3; ++j) {
    int c = j * 1024 + t;
    int pos = c >> 3, swz = c & 7;
    int ci16 = swz ^ (pos & 7);
    int tr = pos >> 6, col = pos & 63;
    int yy = y0 - 1 + tr;
    if ((unsigned)yy < 64u)
      bgOff[j] = ((((b << 6) + yy) << 6) + col) * 512 + ci16 * 8;
    else
      bgOff[j] = 8 * 64 * 64 * 512 + col * 512 + ci16 * 8;   // zero page
  }
  // A staging gather offsets; 2 chunks/thread cover 256 o-rows.
  int agOff[2];
#pragma unroll
  for (int j = 0; j < 2; ++j) {
    int c = j * 1024 + t;
    int ol = c >> 3, swz = c & 7;
    int ci16 = swz ^ (ol & 7);
    agOff[j] = (o0 + ol) * 512 + ci16 * 8;
  }

  f32x4 acc[16];
#pragma unroll
  for (int i = 0; i < 16; ++i) acc[i] = (f32x4)0.f;

  // A read addressing: ol = og*64 + mf*16 + l15; xor = ol&7 = l15&7 (mf-independent)
  const int aB0 = og * 512 + l15 * 8;           // chunk-index base
  const int aXorS = l15 & 7;

  // prologue: stage B[cib0] (3) and A[tap 0,0] (2)
#pragma unroll
  for (int j = 0; j < 3; ++j)
    gld16(&ldsB[0][(j * 1024 + w * 64) * 8], xs + bgOff[j]);
#pragma unroll
  for (int j = 0; j < 2; ++j)
    gld16(&ldsA[0][(j * 1024 + w * 64) * 8], wt + agOff[j]);

#pragma unroll 1
  for (int cib = 0; cib < 8; ++cib) {
    const u16* bR = &ldsB[cib & 1][0];
#pragma unroll
    for (int khw = 0; khw < 9; ++khw) {
      // tap boundary: my A-stage for this tap (issued last tap) must have landed.
      // After the B-issue tap (khw==6) allow the 3 B loads to stay in flight.
      if (khw == 7) { asm volatile("s_waitcnt vmcnt(3)" ::: "memory"); }
      else          { asm volatile("s_waitcnt vmcnt(0)" ::: "memory"); }
      __builtin_amdgcn_s_barrier();
      __builtin_amdgcn_sched_barrier(0);

      const int par = (cib + khw) & 1;
      const u16* aR = &ldsA[par][0];
      u16* aW = (u16*)&ldsA[par ^ 1][0];
      const int nkhw = (khw == 8) ? 0 : khw + 1;
      const int ncib = (khw == 8) ? ((cib + 1) & 7) : cib;

      const int kh = khw / 3, kw = khw % 3;
      const int tr = wrw + kh;                 // 0..5, always in-range (zero page)
      int bBase[4], bXor[4];
      unsigned cmask[4];
#pragma unroll
      for (int nf = 0; nf < 4; ++nf) {
        int ci = nf * 16 + l15 + kw - 1;
        cmask[nf] = ((kw == 0 && nf == 0) || (kw == 2 && nf == 3))
                        ? (unsigned)((unsigned)ci > 63u) : 0u;
        ci &= 63;
        bBase[nf] = (tr * 64 + ci) * 8;
        bXor[nf] = ci & 7;
      }

      // ---- phase 0: ds(ks0) + stage A-chunk 0 -> barrier -> 16 MFMA ----
      bf16x8 af0[4], bv0[4];
      {
        const int kci = quad;
#pragma unroll
        for (int mf = 0; mf < 4; ++mf)
          af0[mf] = *(const bf16x8*)(aR + (aB0 + mf * 128 + (kci ^ aXorS)) * 8);
#pragma unroll
        for (int nf = 0; nf < 4; ++nf) {
          bf16x8 v = *(const bf16x8*)(bR + (bBase[nf] + (kci ^ bXor[nf])) * 8);
          bf16x8 z = {0, 0, 0, 0, 0, 0, 0, 0};
          bv0[nf] = cmask[nf] ? z : v;
        }
      }
      gld16(aW + (0 * 1024 + w * 64) * 8, wt + agOff[0] + nkhw * 262144 + ncib * 64);
      __builtin_amdgcn_s_barrier();
      __builtin_amdgcn_s_setprio(1);
#pragma unroll
      for (int mf = 0; mf < 4; ++mf)
#pragma unroll
        for (int nf = 0; nf < 4; ++nf)
          acc[mf * 4 + nf] = __builtin_amdgcn_mfma_f32_16x16x32_bf16(
              af0[mf], bv0[nf], acc[mf * 4 + nf], 0, 0, 0);
      __builtin_amdgcn_s_setprio(0);

      // ---- phase 1: ds(ks1) + stage A-chunk 1 (+B at khw==6) -> barrier -> 16 MFMA
      bf16x8 af1[4], bv1[4];
      {
        const int kci = 4 + quad;
#pragma unroll
        for (int mf = 0; mf < 4; ++mf)
          af1[mf] = *(const bf16x8*)(aR + (aB0 + mf * 128 + (kci ^ aXorS)) * 8);
#pragma unroll
        for (int nf = 0; nf < 4; ++nf) {
          bf16x8 v = *(const bf16x8*)(bR + (bBase[nf] + (kci ^ bXor[nf])) * 8);
          bf16x8 z = {0, 0, 0, 0, 0, 0, 0, 0};
          bv1[nf] = cmask[nf] ? z : v;
        }
      }
      gld16(aW + (1 * 1024 + w * 64) * 8, wt + agOff[1] + nkhw * 262144 + ncib * 64);
      if (khw == 6) {
        u16* bW = (u16*)&ldsB[(cib & 1) ^ 1][0];
        const int pc = (cib + 1) & 7;
#pragma unroll
        for (int j = 0; j < 3; ++j)
          gld16(bW + (j * 1024 + w * 64) * 8, xs + bgOff[j] + pc * 64);
      }
      __builtin_amdgcn_s_barrier();
      __builtin_amdgcn_s_setprio(1);
#pragma unroll
      for (int mf = 0; mf < 4; ++mf)
#pragma unroll
        for (int nf = 0; nf < 4; ++nf)
          acc[mf * 4 + nf] = __builtin_amdgcn_mfma_f32_16x16x32_bf16(
              af1[mf], bv1[nf], acc[mf * 4 + nf], 0, 0, 0);
      __builtin_amdgcn_s_setprio(0);
    }
  }
  // drain the wrapped tail stage before LDS goes away
  asm volatile("s_waitcnt vmcnt(0)" ::: "memory");

  // epilogue: scale + noise + bias + leaky_relu*sqrt(2), f32 store
  const float nwv = nwp[0];
  const int y = y0 + wrw;
#pragma unroll
  for (int mf = 0; mf < 4; ++mf) {
#pragma unroll
    for (int r = 0; r < 4; ++r) {
      int o = o0 + og * 64 + mf * 16 + quad * 4 + r;
      float es = esc[(b << 9) + o];
      float ab = abias[o];
      int rowbase = ((((b << 9) + o) << 6) | y) << 6;
#pragma unroll
      for (int nf = 0; nf < 4; ++nf) {
        int col = nf * 16 + l15;
        int idx = rowbase | col;
        float v = acc[mf * 4 + nf][r] * es + nwv * noise[idx] + ab;
        v = (v < 0.f ? 0.2f * v : v) * 1.4142135623730951f;
        out[idx] = v;
      }
    }
  }
}

extern "C" void kernel_launch(void* const* d_in, const int* in_sizes, int n_in,
                              void* d_out, int out_size, void* d_ws, size_t ws_size,
                              hipStream_t stream) {
  const float* x      = (const float*)d_in[0];
  const float* style  = (const float*)d_in[1];
  const float* noise  = (const float*)d_in[2];
  const float* weight = (const float*)d_in[3];
  const float* mw     = (const float*)d_in[4];
  const float* mb     = (const float*)d_in[5];
  const float* nw     = (const float*)d_in[6];
  const float* ab     = (const float*)d_in[7];
  float* out = (float*)d_out;

  char* ws = (char*)d_ws;
  float* s   = (float*)(ws + WS_S);
  float* esc = (float*)(ws + WS_ESC);
  float* wsq = (float*)(ws + WS_WSQ);
  u16* wt    = (u16*)(ws + WS_WT);
  u16* xs    = (u16*)(ws + WS_XS);
  u16* zbuf  = (u16*)(ws + WS_Z);

  k_pre1<<<2080, 256, 0, stream>>>(style, mw, mb, weight, s, wsq, (u64*)zbuf);
  k_pre2<<<6144, 256, 0, stream>>>(wsq, s, weight, x, esc, wt, xs);
  k_conv<<<dim3(2, 128), 1024, 0, stream>>>(wt, xs, esc, noise, nw, ab, out);
}

// Round 6
// 364.394 us; speedup vs baseline: 1.0738x; 1.0738x over previous
//
#include <hip/hip_runtime.h>
#include <hip/hip_bf16.h>

typedef unsigned short u16;
typedef unsigned long long u64;
typedef short bf16x8 __attribute__((ext_vector_type(8)));
typedef float f32x4 __attribute__((ext_vector_type(4)));

#define EQ_SCALE   0.04419417382415922f     /* 1/sqrt(512) */
#define CONV_SCALE 0.014731391274719738f    /* 1/sqrt(512*9) */

// workspace layout (bytes)
#define WS_S   0                                  // f32 [8][512]
#define WS_ESC (16*1024)                          // f32 [8][512]  = conv_scale*demod
#define WS_WSQ (32*1024)                          // f32 [512][512]
#define WS_WT  (32*1024 + 1024*1024)              // bf16 [9][512][512]  (khw, o, ci)
#define WS_XS  (WS_WT + 9*512*512*2)              // bf16 [8][64][64][512] (b, y, x, ci)
#define WS_Z   (WS_XS + 8*64*64*512*2)            // bf16 zero page, 64 KB

__device__ __forceinline__ void gld16(void* l, const void* g) {
  __builtin_amdgcn_global_load_lds((const __attribute__((address_space(1))) void*)g,
                                   (__attribute__((address_space(3))) void*)l,
                                   16, 0, 0);
}

// round-to-nearest-even f32 -> bf16 bits
__device__ __forceinline__ u16 f2b_rne(float f) {
  union { float f; unsigned int i; } c; c.f = f;
  unsigned int r = (c.i + 0x7FFFu + ((c.i >> 16) & 1u)) >> 16;
  return (u16)r;
}

// fused prep 1: zero page (32 blocks) + wsq (1024 blocks) + style (1024 blocks)
__global__ void __launch_bounds__(256) k_pre1(
    const float* __restrict__ style, const float* __restrict__ mw,
    const float* __restrict__ mb, const float* __restrict__ w,
    float* __restrict__ s, float* __restrict__ wsq, u64* __restrict__ z) {
  int bid = blockIdx.x, t = threadIdx.x;
  if (bid < 32) { z[bid * 256 + t] = 0ull; return; }
  if (bid < 1056) {                              // wsq[o][i] = sum_khw w[o][i][khw]^2
    int idx = (bid - 32) * 256 + t;
    const float* p = w + idx * 9;
    float a = 0.f;
#pragma unroll
    for (int k = 0; k < 9; ++k) { float v = p[k]; a += v * v; }
    wsq[idx] = a;
    return;
  }
  // style: one wave per output, s[b][i] = eq_scale*dot(style[b], mw[i]) + mb[i]
  int g = (bid - 1056) * 4 + (t >> 6);           // 4096
  int lane = t & 63;
  int b = g >> 9, i = g & 511;
  const float4* sr = (const float4*)(style + (b << 9));
  const float4* wr = (const float4*)(mw + (i << 9));
  float acc = 0.f;
#pragma unroll
  for (int j = 0; j < 2; ++j) {
    float4 a4 = sr[lane * 2 + j];
    float4 w4 = wr[lane * 2 + j];
    acc += a4.x * w4.x + a4.y * w4.y + a4.z * w4.z + a4.w * w4.w;
  }
#pragma unroll
  for (int off = 32; off; off >>= 1) acc += __shfl_xor(acc, off);
  if (lane == 0) s[g] = acc * EQ_SCALE + mb[i];
}

// fused prep 2: esc (1024) + wt relayout (1024) + xs transpose/scale (4096)
__global__ void __launch_bounds__(256) k_pre2(
    const float* __restrict__ wsq, const float* __restrict__ s,
    const float* __restrict__ w, const float* __restrict__ x,
    float* __restrict__ esc, u16* __restrict__ wt, u16* __restrict__ xs) {
  __shared__ u16 tile[64 * 66];
  int bid = blockIdx.x, t = threadIdx.x;
  if (bid < 1024) {                              // esc, one wave per output
    int g = bid * 4 + (t >> 6);
    int lane = t & 63;
    int b = g >> 9, o = g & 511;
    const float4* wr = (const float4*)(wsq + (o << 9));
    const float4* sr = (const float4*)(s + (b << 9));
    float a = 0.f;
#pragma unroll
    for (int j = 0; j < 2; ++j) {
      float4 wv = wr[lane * 2 + j];
      float4 sv = sr[lane * 2 + j];
      a += wv.x*sv.x*sv.x + wv.y*sv.y*sv.y + wv.z*sv.z*sv.z + wv.w*sv.w*sv.w;
    }
#pragma unroll
    for (int off = 32; off; off >>= 1) a += __shfl_xor(a, off);
    if (lane == 0) esc[g] = CONV_SCALE * rsqrtf(CONV_SCALE * CONV_SCALE * a + 1e-8f);
    return;
  }
  if (bid < 2048) {                              // wt[khw][o][i] = bf16(w[o][i][khw])
    int idx = (bid - 1024) * 256 + t;
    const float* p = w + idx * 9;
#pragma unroll
    for (int k = 0; k < 9; ++k) wt[k * 262144 + idx] = f2b_rne(p[k]);
    return;
  }
  // xs[b][y][x][i] = bf16(x[b][i][y][x] * s[b][i])
  int v = bid - 2048;                            // 0..4095
  int by = v & 511, i0 = (v >> 9) << 6;
  int b = by >> 6, y = by & 63;
  int wv = t >> 6, lane = t & 63;
  for (int k = 0; k < 16; ++k) {
    int il = wv + (k << 2);
    int i = i0 + il;
    float val = x[((((b << 9) + i) << 6) | y) << 6 | lane] * s[(b << 9) + i];
    tile[lane * 66 + il] = f2b_rne(val);
  }
  __syncthreads();
  // vectorized store: thread = (row=t>>4, qt=t&15); 4 iters of short4
  int row = t >> 4, qt = t & 15;
  for (int k = 0; k < 4; ++k) {
    int xc = row + k * 16;
    short4 o4;
    o4.x = (short)tile[xc * 66 + qt * 4 + 0];
    o4.y = (short)tile[xc * 66 + qt * 4 + 1];
    o4.z = (short)tile[xc * 66 + qt * 4 + 2];
    o4.w = (short)tile[xc * 66 + qt * 4 + 3];
    *(short4*)(&xs[((((b << 6) | y) << 6 | xc) << 9) + i0 + qt * 4]) = o4;
  }
}

// Conv: implicit GEMM, m201 8-phase-template geometry. Block 256(o) x 256(pos),
// 512 threads, 8 waves (2 o-halves x 4 rows), wave tile 128(o) x 64(pos),
// acc[32] = 128 VGPR. amdgpu_waves_per_eu(2,2) pins the VGPR cap at 256 so the
// allocator cannot spill-for-occupancy (R2/R4/R5 failure mode).
// Per tap (K=64): 4 phases of {ds_read burst + 1 stage-issue -> s_barrier ->
// lgkmcnt(0) -> setprio 16-MFMA setprio -> s_barrier}; reads balanced 8/8/4/4;
// ONE counted vmcnt per tap. LDS = 2x32KB (A) + 2x48KB (B) = 160 KB, 1 block/CU.
__attribute__((amdgpu_waves_per_eu(2, 2)))
__global__ void __launch_bounds__(512) k_conv(
    const u16* __restrict__ wt, const u16* __restrict__ xs,
    const u16* __restrict__ zbuf,
    const float* __restrict__ esc, const float* __restrict__ noise,
    const float* __restrict__ nwp, const float* __restrict__ abias,
    float* __restrict__ out) {
  __shared__ __align__(16) u16 ldsA[2][256 * 64];   // 2 x 32 KB, xor-swizzled chunks
  __shared__ __align__(16) u16 ldsB[2][384 * 64];   // 2 x 48 KB: 6 input rows x 64 cols

  const int t = threadIdx.x;
  const int w = t >> 6, lane = t & 63;
  const int wm = w >> 2, wrw = w & 3;           // 2(o-group of 128) x 4(row) wave grid
  const int quad = lane >> 4, l15 = lane & 15;

  // XCD pinning: xcds 0-3 own o-half 0, xcds 4-7 own o-half 1 (2.25 MB wt/half).
  const int flat = blockIdx.y * 2 + blockIdx.x;   // 0..255
  const int xcd = flat & 7, rest = flat >> 3;     // 8 x 32
  const int o0 = (xcd >> 2) << 8;                 // 0 or 256
  const int nt = (rest << 2) | (xcd & 3);         // 0..127, bijective
  const int b = nt >> 4, y0 = (nt & 15) << 2;     // 4 output rows per tile

  // B staging source pointers; chunk j covers LDS row tr==j (input row y0-1+j).
  // OOB rows redirect to the zero page -> no row masking anywhere in compute.
  const u16* bgp[6];
#pragma unroll
  for (int j = 0; j < 6; ++j) {
    int c = j * 512 + t;
    int pos = c >> 3, swz = c & 7;
    int ci16 = swz ^ (pos & 7);
    int col = pos & 63;
    int yy = y0 - 1 + j;
    if ((unsigned)yy < 64u)
      bgp[j] = xs + ((((b << 6) + yy) << 6) + col) * 512 + ci16 * 8;
    else
      bgp[j] = zbuf + col * 512 + ci16 * 8;
  }
  // A staging gather offsets (element units; add khw/cib at issue). 4 chunks/thread.
  int agOff[4];
#pragma unroll
  for (int j = 0; j < 4; ++j) {
    int c = j * 512 + t;
    int ol = c >> 3, swz = c & 7;
    int ci16 = swz ^ (ol & 7);
    agOff[j] = (o0 + ol) * 512 + ci16 * 8;
  }

  f32x4 acc[32];
#pragma unroll
  for (int i = 0; i < 32; ++i) acc[i] = (f32x4)0.f;

  // A read addressing: ol = wm*128 + mf*16 + l15; xor = ol&7 = l15&7 (mf-independent)
  const int aB0 = wm * 1024 + l15 * 8;          // chunk-index base
  const int aXorS = l15 & 7;

  // prologue: stage B[cib0] (6) and A[tap 0,0] (4); publish
#pragma unroll
  for (int j = 0; j < 6; ++j)
    gld16(&ldsB[0][(j * 512 + w * 64) * 8], bgp[j]);
#pragma unroll
  for (int j = 0; j < 4; ++j)
    gld16(&ldsA[0][(j * 512 + w * 64) * 8], wt + agOff[j]);
  asm volatile("s_waitcnt vmcnt(0)" ::: "memory");
  __builtin_amdgcn_s_barrier();

#pragma unroll 1
  for (int cib = 0; cib < 8; ++cib) {
    const u16* bR = &ldsB[cib & 1][0];
#pragma unroll
    for (int khw = 0; khw < 9; ++khw) {
      const int par = (cib + khw) & 1;
      const u16* aR = &ldsA[par][0];
      u16* aW = (u16*)&ldsA[par ^ 1][0];
      const int nkhw = (khw == 8) ? 0 : khw + 1;
      const int ncib = (khw == 8) ? ((cib + 1) & 7) : cib;
      const int aStageOff = nkhw * 262144 + ncib * 64;

      const int kh = khw / 3, kw = khw % 3;
      const int tr = wrw + kh;                 // 0..5, always in-range (zero page)
      int bBase[4], bXor[4];
      unsigned cmask[4];
#pragma unroll
      for (int nf = 0; nf < 4; ++nf) {
        int ci = nf * 16 + l15 + kw - 1;
        cmask[nf] = ((kw == 0 && nf == 0) || (kw == 2 && nf == 3))
                        ? (unsigned)((unsigned)ci > 63u) : 0u;
        ci &= 63;
        bBase[nf] = (tr * 64 + ci) * 8;
        bXor[nf] = ci & 7;
      }
      const bf16x8 zf = {0, 0, 0, 0, 0, 0, 0, 0};

      bf16x8 af[4], bv0[4], bv1[4];

      // ---------------- phase 0: ks=0, mfh=0 (8 ds reads) ----------------
#pragma unroll
      for (int m = 0; m < 4; ++m)
        af[m] = *(const bf16x8*)(aR + (aB0 + m * 128 + (quad ^ aXorS)) * 8);
#pragma unroll
      for (int nf = 0; nf < 4; ++nf) {
        bf16x8 v = *(const bf16x8*)(bR + (bBase[nf] + (quad ^ bXor[nf])) * 8);
        bv0[nf] = cmask[nf] ? zf : v;
      }
      gld16(aW + (0 * 512 + w * 64) * 8, wt + agOff[0] + aStageOff);
      __builtin_amdgcn_s_barrier();
      asm volatile("s_waitcnt lgkmcnt(0)" ::: "memory");
      __builtin_amdgcn_sched_barrier(0);
      __builtin_amdgcn_s_setprio(1);
#pragma unroll
      for (int m = 0; m < 4; ++m)
#pragma unroll
        for (int nf = 0; nf < 4; ++nf)
          acc[m * 4 + nf] = __builtin_amdgcn_mfma_f32_16x16x32_bf16(
              af[m], bv0[nf], acc[m * 4 + nf], 0, 0, 0);
      __builtin_amdgcn_s_setprio(0);
      __builtin_amdgcn_s_barrier();

      // ---------------- phase 1: ks=0, mfh=1 (+prefetch B ks=1: 8 reads) --
#pragma unroll
      for (int m = 0; m < 4; ++m)
        af[m] = *(const bf16x8*)(aR + (aB0 + (m + 4) * 128 + (quad ^ aXorS)) * 8);
#pragma unroll
      for (int nf = 0; nf < 4; ++nf) {
        bf16x8 v = *(const bf16x8*)(bR + (bBase[nf] + ((4 + quad) ^ bXor[nf])) * 8);
        bv1[nf] = cmask[nf] ? zf : v;
      }
      gld16(aW + (1 * 512 + w * 64) * 8, wt + agOff[1] + aStageOff);
      __builtin_amdgcn_s_barrier();
      asm volatile("s_waitcnt lgkmcnt(0)" ::: "memory");
      __builtin_amdgcn_sched_barrier(0);
      __builtin_amdgcn_s_setprio(1);
#pragma unroll
      for (int m = 0; m < 4; ++m)
#pragma unroll
        for (int nf = 0; nf < 4; ++nf)
          acc[(m + 4) * 4 + nf] = __builtin_amdgcn_mfma_f32_16x16x32_bf16(
              af[m], bv0[nf], acc[(m + 4) * 4 + nf], 0, 0, 0);
      __builtin_amdgcn_s_setprio(0);
      __builtin_amdgcn_s_barrier();

      // ---------------- phase 2: ks=1, mfh=0 (4 reads) --------------------
#pragma unroll
      for (int m = 0; m < 4; ++m)
        af[m] = *(const bf16x8*)(aR + (aB0 + m * 128 + ((4 + quad) ^ aXorS)) * 8);
      gld16(aW + (2 * 512 + w * 64) * 8, wt + agOff[2] + aStageOff);
      if (khw == 6) {
        u16* bW = (u16*)&ldsB[(cib & 1) ^ 1][0];
        const int pc = (cib + 1) & 7;
#pragma unroll
        for (int j = 0; j < 3; ++j)
          gld16(bW + (j * 512 + w * 64) * 8, bgp[j] + pc * 64);
      }
      __builtin_amdgcn_s_barrier();
      asm volatile("s_waitcnt lgkmcnt(0)" ::: "memory");
      __builtin_amdgcn_sched_barrier(0);
      __builtin_amdgcn_s_setprio(1);
#pragma unroll
      for (int m = 0; m < 4; ++m)
#pragma unroll
        for (int nf = 0; nf < 4; ++nf)
          acc[m * 4 + nf] = __builtin_amdgcn_mfma_f32_16x16x32_bf16(
              af[m], bv1[nf], acc[m * 4 + nf], 0, 0, 0);
      __builtin_amdgcn_s_setprio(0);
      __builtin_amdgcn_s_barrier();

      // ---------------- phase 3: ks=1, mfh=1 (4 reads) --------------------
#pragma unroll
      for (int m = 0; m < 4; ++m)
        af[m] = *(const bf16x8*)(aR + (aB0 + (m + 4) * 128 + ((4 + quad) ^ aXorS)) * 8);
      gld16(aW + (3 * 512 + w * 64) * 8, wt + agOff[3] + aStageOff);
      if (khw == 6) {
        u16* bW = (u16*)&ldsB[(cib & 1) ^ 1][0];
        const int pc = (cib + 1) & 7;
#pragma unroll
        for (int j = 3; j < 6; ++j)
          gld16(bW + (j * 512 + w * 64) * 8, bgp[j] + pc * 64);
      }
      __builtin_amdgcn_s_barrier();
      asm volatile("s_waitcnt lgkmcnt(0)" ::: "memory");
      __builtin_amdgcn_sched_barrier(0);
      __builtin_amdgcn_s_setprio(1);
#pragma unroll
      for (int m = 0; m < 4; ++m)
#pragma unroll
        for (int nf = 0; nf < 4; ++nf)
          acc[(m + 4) * 4 + nf] = __builtin_amdgcn_mfma_f32_16x16x32_bf16(
              af[m], bv1[nf], acc[(m + 4) * 4 + nf], 0, 0, 0);
      __builtin_amdgcn_s_setprio(0);
      // tap boundary: my 4 A-stage chunks must land before next tap reads them.
      // On the B-prefetch tap, the 3 newest loads (B3-5) may stay in flight.
      if (khw == 6) { asm volatile("s_waitcnt vmcnt(3)" ::: "memory"); }
      else          { asm volatile("s_waitcnt vmcnt(0)" ::: "memory"); }
      __builtin_amdgcn_s_barrier();
    }
  }
  // drain the wrapped tail stage before the kernel ends
  asm volatile("s_waitcnt vmcnt(0)" ::: "memory");

  // epilogue: scale + noise + bias + leaky_relu*sqrt(2), f32 store
  const float nwv = nwp[0];
  const int y = y0 + wrw;
#pragma unroll
  for (int mf = 0; mf < 8; ++mf) {
#pragma unroll
    for (int r = 0; r < 4; ++r) {
      int o = o0 + wm * 128 + mf * 16 + quad * 4 + r;
      float es = esc[(b << 9) + o];
      float ab = abias[o];
      int rowbase = ((((b << 9) + o) << 6) | y) << 6;
#pragma unroll
      for (int nf = 0; nf < 4; ++nf) {
        int col = nf * 16 + l15;
        int idx = rowbase | col;
        float v = acc[mf * 4 + nf][r] * es + nwv * noise[idx] + ab;
        v = (v < 0.f ? 0.2f * v : v) * 1.4142135623730951f;
        out[idx] = v;
      }
    }
  }
}

extern "C" void kernel_launch(void* const* d_in, const int* in_sizes, int n_in,
                              void* d_out, int out_size, void* d_ws, size_t ws_size,
                              hipStream_t stream) {
  const float* x      = (const float*)d_in[0];
  const float* style  = (const float*)d_in[1];
  const float* noise  = (const float*)d_in[2];
  const float* weight = (const float*)d_in[3];
  const float* mw     = (const float*)d_in[4];
  const float* mb     = (const float*)d_in[5];
  const float* nw     = (const float*)d_in[6];
  const float* ab     = (const float*)d_in[7];
  float* out = (float*)d_out;

  char* ws = (char*)d_ws;
  float* s   = (float*)(ws + WS_S);
  float* esc = (float*)(ws + WS_ESC);
  float* wsq = (float*)(ws + WS_WSQ);
  u16* wt    = (u16*)(ws + WS_WT);
  u16* xs    = (u16*)(ws + WS_XS);
  u16* zbuf  = (u16*)(ws + WS_Z);

  k_pre1<<<2080, 256, 0, stream>>>(style, mw, mb, weight, s, wsq, (u64*)zbuf);
  k_pre2<<<6144, 256, 0, stream>>>(wsq, s, weight, x, esc, wt, xs);
  k_conv<<<dim3(2, 128), 512, 0, stream>>>(wt, xs, zbuf, esc, noise, nw, ab, out);
}

// Round 8
// 361.117 us; speedup vs baseline: 1.0835x; 1.0091x over previous
//
#include <hip/hip_runtime.h>
#include <hip/hip_bf16.h>

typedef unsigned short u16;
typedef unsigned long long u64;
typedef short bf16x8 __attribute__((ext_vector_type(8)));
typedef float f32x4 __attribute__((ext_vector_type(4)));

#define EQ_SCALE   0.04419417382415922f     /* 1/sqrt(512) */
#define CONV_SCALE 0.014731391274719738f    /* 1/sqrt(512*9) */

// workspace layout (bytes)
#define WS_S   0                                  // f32 [8][512]
#define WS_ESC (16*1024)                          // f32 [8][512]  = conv_scale*demod
#define WS_WSQ (32*1024)                          // f32 [512][512]
#define WS_WT  (32*1024 + 1024*1024)              // bf16 [9][512][512]  (khw, o, ci)
#define WS_XS  (WS_WT + 9*512*512*2)              // bf16 [8][64][64][512] (b, y, x, ci)
#define WS_Z   (WS_XS + 8*64*64*512*2)            // bf16 zero page, 64 KB

__device__ __forceinline__ void gld16(void* l, const void* g) {
  __builtin_amdgcn_global_load_lds((const __attribute__((address_space(1))) void*)g,
                                   (__attribute__((address_space(3))) void*)l,
                                   16, 0, 0);
}

// MFMA with the accumulator pinned to AGPRs ("+a") — keeps the 128-f32 acc out
// of the arch-VGPR file (R2/R4/R5/R6 spill failure). MUST be volatile: inline
// asm is opaque to the GCN hazard recognizer, so a non-volatile copy can be
// sunk next to its accvgpr_read use with zero hazard distance (R7 corruption).
__device__ __forceinline__ f32x4 mfma16(bf16x8 a, bf16x8 b, f32x4 c) {
  asm volatile("v_mfma_f32_16x16x32_bf16 %0, %1, %2, %0" : "+a"(c) : "v"(a), "v"(b));
  return c;
}

// round-to-nearest-even f32 -> bf16 bits
__device__ __forceinline__ u16 f2b_rne(float f) {
  union { float f; unsigned int i; } c; c.f = f;
  unsigned int r = (c.i + 0x7FFFu + ((c.i >> 16) & 1u)) >> 16;
  return (u16)r;
}

// fused prep 1: zero page (32 blocks) + wsq (1024 blocks) + style (1024 blocks)
__global__ void __launch_bounds__(256) k_pre1(
    const float* __restrict__ style, const float* __restrict__ mw,
    const float* __restrict__ mb, const float* __restrict__ w,
    float* __restrict__ s, float* __restrict__ wsq, u64* __restrict__ z) {
  int bid = blockIdx.x, t = threadIdx.x;
  if (bid < 32) { z[bid * 256 + t] = 0ull; return; }
  if (bid < 1056) {                              // wsq[o][i] = sum_khw w[o][i][khw]^2
    int idx = (bid - 32) * 256 + t;
    const float* p = w + idx * 9;
    float a = 0.f;
#pragma unroll
    for (int k = 0; k < 9; ++k) { float v = p[k]; a += v * v; }
    wsq[idx] = a;
    return;
  }
  // style: one wave per output, s[b][i] = eq_scale*dot(style[b], mw[i]) + mb[i]
  int g = (bid - 1056) * 4 + (t >> 6);           // 4096
  int lane = t & 63;
  int b = g >> 9, i = g & 511;
  const float4* sr = (const float4*)(style + (b << 9));
  const float4* wr = (const float4*)(mw + (i << 9));
  float acc = 0.f;
#pragma unroll
  for (int j = 0; j < 2; ++j) {
    float4 a4 = sr[lane * 2 + j];
    float4 w4 = wr[lane * 2 + j];
    acc += a4.x * w4.x + a4.y * w4.y + a4.z * w4.z + a4.w * w4.w;
  }
#pragma unroll
  for (int off = 32; off; off >>= 1) acc += __shfl_xor(acc, off);
  if (lane == 0) s[g] = acc * EQ_SCALE + mb[i];
}

// fused prep 2: esc (1024) + wt relayout (1024) + xs transpose/scale (4096)
__global__ void __launch_bounds__(256) k_pre2(
    const float* __restrict__ wsq, const float* __restrict__ s,
    const float* __restrict__ w, const float* __restrict__ x,
    float* __restrict__ esc, u16* __restrict__ wt, u16* __restrict__ xs) {
  __shared__ u16 tile[64 * 66];
  int bid = blockIdx.x, t = threadIdx.x;
  if (bid < 1024) {                              // esc, one wave per output
    int g = bid * 4 + (t >> 6);
    int lane = t & 63;
    int b = g >> 9, o = g & 511;
    const float4* wr = (const float4*)(wsq + (o << 9));
    const float4* sr = (const float4*)(s + (b << 9));
    float a = 0.f;
#pragma unroll
    for (int j = 0; j < 2; ++j) {
      float4 wv = wr[lane * 2 + j];
      float4 sv = sr[lane * 2 + j];
      a += wv.x*sv.x*sv.x + wv.y*sv.y*sv.y + wv.z*sv.z*sv.z + wv.w*sv.w*sv.w;
    }
#pragma unroll
    for (int off = 32; off; off >>= 1) a += __shfl_xor(a, off);
    if (lane == 0) esc[g] = CONV_SCALE * rsqrtf(CONV_SCALE * CONV_SCALE * a + 1e-8f);
    return;
  }
  if (bid < 2048) {                              // wt[khw][o][i] = bf16(w[o][i][khw])
    int idx = (bid - 1024) * 256 + t;
    const float* p = w + idx * 9;
#pragma unroll
    for (int k = 0; k < 9; ++k) wt[k * 262144 + idx] = f2b_rne(p[k]);
    return;
  }
  // xs[b][y][x][i] = bf16(x[b][i][y][x] * s[b][i])
  int v = bid - 2048;                            // 0..4095
  int by = v & 511, i0 = (v >> 9) << 6;
  int b = by >> 6, y = by & 63;
  int wv = t >> 6, lane = t & 63;
  for (int k = 0; k < 16; ++k) {
    int il = wv + (k << 2);
    int i = i0 + il;
    float val = x[((((b << 9) + i) << 6) | y) << 6 | lane] * s[(b << 9) + i];
    tile[lane * 66 + il] = f2b_rne(val);
  }
  __syncthreads();
  // vectorized store: thread = (row=t>>4, qt=t&15); 4 iters of short4
  int row = t >> 4, qt = t & 15;
  for (int k = 0; k < 4; ++k) {
    int xc = row + k * 16;
    short4 o4;
    o4.x = (short)tile[xc * 66 + qt * 4 + 0];
    o4.y = (short)tile[xc * 66 + qt * 4 + 1];
    o4.z = (short)tile[xc * 66 + qt * 4 + 2];
    o4.w = (short)tile[xc * 66 + qt * 4 + 3];
    *(short4*)(&xs[((((b << 6) | y) << 6 | xc) << 9) + i0 + qt * 4]) = o4;
  }
}

// Conv: implicit GEMM. Block 256(o) x 256(pos), 512 threads, 8 waves (2 o-halves
// x 4 rows), wave tile 128(o) x 64(pos) -> 42.7 FLOP/LDS-byte. Accumulator acc[32]
// (128 f32) lives in AGPRs via volatile inline-asm MFMA "+a"; hazard fencing:
// sched_barrier(0) + 3x s_nop 7 before any accvgpr_read (epilogue), s_nop 1 at
// cluster entry (VALU-write -> MFMA-src hazard). Per tap: 4 phases {ds burst +
// 1 A-stage-issue -> barrier -> lgkmcnt(0) -> setprio 16-MFMA setprio -> barrier};
// counted vmcnt per tap. LDS = 2x32KB (A) + 2x48KB (B) = 160 KB, 1 block/CU.
__global__ void __launch_bounds__(512) k_conv(
    const u16* __restrict__ wt, const u16* __restrict__ xs,
    const u16* __restrict__ zbuf,
    const float* __restrict__ esc, const float* __restrict__ noise,
    const float* __restrict__ nwp, const float* __restrict__ abias,
    float* __restrict__ out) {
  __shared__ __align__(16) u16 ldsA[2][256 * 64];   // 2 x 32 KB, xor-swizzled chunks
  __shared__ __align__(16) u16 ldsB[2][384 * 64];   // 2 x 48 KB: 6 input rows x 64 cols

  const int t = threadIdx.x;
  const int w = t >> 6, lane = t & 63;
  const int wm = w >> 2, wrw = w & 3;           // 2(o-group of 128) x 4(row) wave grid
  const int quad = lane >> 4, l15 = lane & 15;

  // XCD pinning: xcds 0-3 own o-half 0, xcds 4-7 own o-half 1 (2.25 MB wt/half).
  const int flat = blockIdx.y * 2 + blockIdx.x;   // 0..255
  const int xcd = flat & 7, rest = flat >> 3;     // 8 x 32
  const int o0 = (xcd >> 2) << 8;                 // 0 or 256
  const int nt = (rest << 2) | (xcd & 3);         // 0..127, bijective
  const int b = nt >> 4, y0 = (nt & 15) << 2;     // 4 output rows per tile

  // B staging source pointers; chunk j covers LDS row tr==j (input row y0-1+j).
  // OOB rows redirect to the zero page -> no row masking anywhere in compute.
  const u16* bgp[6];
#pragma unroll
  for (int j = 0; j < 6; ++j) {
    int c = j * 512 + t;
    int pos = c >> 3, swz = c & 7;
    int ci16 = swz ^ (pos & 7);
    int col = pos & 63;
    int yy = y0 - 1 + j;
    if ((unsigned)yy < 64u)
      bgp[j] = xs + ((((b << 6) + yy) << 6) + col) * 512 + ci16 * 8;
    else
      bgp[j] = zbuf + col * 512 + ci16 * 8;
  }
  // A staging gather offsets (element units; add khw/cib at issue). 4 chunks/thread.
  int agOff[4];
#pragma unroll
  for (int j = 0; j < 4; ++j) {
    int c = j * 512 + t;
    int ol = c >> 3, swz = c & 7;
    int ci16 = swz ^ (ol & 7);
    agOff[j] = (o0 + ol) * 512 + ci16 * 8;
  }

  f32x4 acc[32];
#pragma unroll
  for (int i = 0; i < 32; ++i) acc[i] = (f32x4)0.f;

  // A read addressing: ol = wm*128 + mf*16 + l15; xor = ol&7 = l15&7 (mf-independent)
  const int aB0 = wm * 1024 + l15 * 8;          // chunk-index base
  const int aXorS = l15 & 7;

  // prologue: stage B[cib0] (6) and A[tap 0,0] (4); publish
#pragma unroll
  for (int j = 0; j < 6; ++j)
    gld16(&ldsB[0][(j * 512 + w * 64) * 8], bgp[j]);
#pragma unroll
  for (int j = 0; j < 4; ++j)
    gld16(&ldsA[0][(j * 512 + w * 64) * 8], wt + agOff[j]);
  asm volatile("s_waitcnt vmcnt(0)" ::: "memory");
  __builtin_amdgcn_s_barrier();

#pragma unroll 1
  for (int cib = 0; cib < 8; ++cib) {
    const u16* bR = &ldsB[cib & 1][0];
#pragma unroll
    for (int khw = 0; khw < 9; ++khw) {
      const int par = (cib + khw) & 1;
      const u16* aR = &ldsA[par][0];
      u16* aW = (u16*)&ldsA[par ^ 1][0];
      const int nkhw = (khw == 8) ? 0 : khw + 1;
      const int ncib = (khw == 8) ? ((cib + 1) & 7) : cib;
      const int aStageOff = nkhw * 262144 + ncib * 64;

      const int kh = khw / 3, kw = khw % 3;
      const int tr = wrw + kh;                 // 0..5, always in-range (zero page)
      int bBase[4], bXor[4];
      unsigned cmask[4];
#pragma unroll
      for (int nf = 0; nf < 4; ++nf) {
        int ci = nf * 16 + l15 + kw - 1;
        cmask[nf] = ((kw == 0 && nf == 0) || (kw == 2 && nf == 3))
                        ? (unsigned)((unsigned)ci > 63u) : 0u;
        ci &= 63;
        bBase[nf] = (tr * 64 + ci) * 8;
        bXor[nf] = ci & 7;
      }
      const bf16x8 zf = {0, 0, 0, 0, 0, 0, 0, 0};

      bf16x8 af[4], bv0[4], bv1[4];

      // ---------------- phase 0: ks=0, mfh=0 (8 ds reads) ----------------
#pragma unroll
      for (int m = 0; m < 4; ++m)
        af[m] = *(const bf16x8*)(aR + (aB0 + m * 128 + (quad ^ aXorS)) * 8);
#pragma unroll
      for (int nf = 0; nf < 4; ++nf) {
        bf16x8 v = *(const bf16x8*)(bR + (bBase[nf] + (quad ^ bXor[nf])) * 8);
        bv0[nf] = cmask[nf] ? zf : v;
      }
      gld16(aW + (0 * 512 + w * 64) * 8, wt + agOff[0] + aStageOff);
      __builtin_amdgcn_s_barrier();
      asm volatile("s_waitcnt lgkmcnt(0)" ::: "memory");
      __builtin_amdgcn_sched_barrier(0);
      __builtin_amdgcn_s_setprio(1);
      asm volatile("s_nop 1");
#pragma unroll
      for (int m = 0; m < 4; ++m)
#pragma unroll
        for (int nf = 0; nf < 4; ++nf)
          acc[m * 4 + nf] = mfma16(af[m], bv0[nf], acc[m * 4 + nf]);
      __builtin_amdgcn_s_setprio(0);
      __builtin_amdgcn_s_barrier();

      // ---------------- phase 1: ks=0, mfh=1 (+prefetch B ks=1: 8 reads) --
#pragma unroll
      for (int m = 0; m < 4; ++m)
        af[m] = *(const bf16x8*)(aR + (aB0 + (m + 4) * 128 + (quad ^ aXorS)) * 8);
#pragma unroll
      for (int nf = 0; nf < 4; ++nf) {
        bf16x8 v = *(const bf16x8*)(bR + (bBase[nf] + ((4 + quad) ^ bXor[nf])) * 8);
        bv1[nf] = cmask[nf] ? zf : v;
      }
      gld16(aW + (1 * 512 + w * 64) * 8, wt + agOff[1] + aStageOff);
      __builtin_amdgcn_s_barrier();
      asm volatile("s_waitcnt lgkmcnt(0)" ::: "memory");
      __builtin_amdgcn_sched_barrier(0);
      __builtin_amdgcn_s_setprio(1);
      asm volatile("s_nop 1");
#pragma unroll
      for (int m = 0; m < 4; ++m)
#pragma unroll
        for (int nf = 0; nf < 4; ++nf)
          acc[(m + 4) * 4 + nf] = mfma16(af[m], bv0[nf], acc[(m + 4) * 4 + nf]);
      __builtin_amdgcn_s_setprio(0);
      __builtin_amdgcn_s_barrier();

      // ---------------- phase 2: ks=1, mfh=0 (4 reads) --------------------
#pragma unroll
      for (int m = 0; m < 4; ++m)
        af[m] = *(const bf16x8*)(aR + (aB0 + m * 128 + ((4 + quad) ^ aXorS)) * 8);
      gld16(aW + (2 * 512 + w * 64) * 8, wt + agOff[2] + aStageOff);
      if (khw == 6) {
        u16* bW = (u16*)&ldsB[(cib & 1) ^ 1][0];
        const int pc = (cib + 1) & 7;
#pragma unroll
        for (int j = 0; j < 3; ++j)
          gld16(bW + (j * 512 + w * 64) * 8, bgp[j] + pc * 64);
      }
      __builtin_amdgcn_s_barrier();
      asm volatile("s_waitcnt lgkmcnt(0)" ::: "memory");
      __builtin_amdgcn_sched_barrier(0);
      __builtin_amdgcn_s_setprio(1);
      asm volatile("s_nop 1");
#pragma unroll
      for (int m = 0; m < 4; ++m)
#pragma unroll
        for (int nf = 0; nf < 4; ++nf)
          acc[m * 4 + nf] = mfma16(af[m], bv1[nf], acc[m * 4 + nf]);
      __builtin_amdgcn_s_setprio(0);
      __builtin_amdgcn_s_barrier();

      // ---------------- phase 3: ks=1, mfh=1 (4 reads) --------------------
#pragma unroll
      for (int m = 0; m < 4; ++m)
        af[m] = *(const bf16x8*)(aR + (aB0 + (m + 4) * 128 + ((4 + quad) ^ aXorS)) * 8);
      gld16(aW + (3 * 512 + w * 64) * 8, wt + agOff[3] + aStageOff);
      if (khw == 6) {
        u16* bW = (u16*)&ldsB[(cib & 1) ^ 1][0];
        const int pc = (cib + 1) & 7;
#pragma unroll
        for (int j = 3; j < 6; ++j)
          gld16(bW + (j * 512 + w * 64) * 8, bgp[j] + pc * 64);
      }
      __builtin_amdgcn_s_barrier();
      asm volatile("s_waitcnt lgkmcnt(0)" ::: "memory");
      __builtin_amdgcn_sched_barrier(0);
      __builtin_amdgcn_s_setprio(1);
      asm volatile("s_nop 1");
#pragma unroll
      for (int m = 0; m < 4; ++m)
#pragma unroll
        for (int nf = 0; nf < 4; ++nf)
          acc[(m + 4) * 4 + nf] = mfma16(af[m], bv1[nf], acc[(m + 4) * 4 + nf]);
      __builtin_amdgcn_s_setprio(0);
      // tap boundary: my 4 A-stage chunks must land before next tap reads them.
      // On the B-prefetch tap, the 3 newest loads (B3-5) may stay in flight.
      if (khw == 6) { asm volatile("s_waitcnt vmcnt(3)" ::: "memory"); }
      else          { asm volatile("s_waitcnt vmcnt(0)" ::: "memory"); }
      __builtin_amdgcn_s_barrier();
    }
  }
  // drain the wrapped tail stage; then fence the XDL pipe before ANY
  // accvgpr_read of acc (inline-asm MFMA is invisible to the hazard
  // recognizer — without this the epilogue reads race the final MFMAs).
  asm volatile("s_waitcnt vmcnt(0)" ::: "memory");
  __builtin_amdgcn_sched_barrier(0);
  asm volatile("s_nop 7\n\ts_nop 7\n\ts_nop 7");
  __builtin_amdgcn_sched_barrier(0);

  // epilogue: scale + noise + bias + leaky_relu*sqrt(2), f32 store
  const float nwv = nwp[0];
  const int y = y0 + wrw;
#pragma unroll
  for (int mf = 0; mf < 8; ++mf) {
#pragma unroll
    for (int r = 0; r < 4; ++r) {
      int o = o0 + wm * 128 + mf * 16 + quad * 4 + r;
      float es = esc[(b << 9) + o];
      float ab = abias[o];
      int rowbase = ((((b << 9) + o) << 6) | y) << 6;
#pragma unroll
      for (int nf = 0; nf < 4; ++nf) {
        int col = nf * 16 + l15;
        int idx = rowbase | col;
        float v = acc[mf * 4 + nf][r] * es + nwv * noise[idx] + ab;
        v = (v < 0.f ? 0.2f * v : v) * 1.4142135623730951f;
        out[idx] = v;
      }
    }
  }
}

extern "C" void kernel_launch(void* const* d_in, const int* in_sizes, int n_in,
                              void* d_out, int out_size, void* d_ws, size_t ws_size,
                              hipStream_t stream) {
  const float* x      = (const float*)d_in[0];
  const float* style  = (const float*)d_in[1];
  const float* noise  = (const float*)d_in[2];
  const float* weight = (const float*)d_in[3];
  const float* mw     = (const float*)d_in[4];
  const float* mb     = (const float*)d_in[5];
  const float* nw     = (const float*)d_in[6];
  const float* ab     = (const float*)d_in[7];
  float* out = (float*)d_out;

  char* ws = (char*)d_ws;
  float* s   = (float*)(ws + WS_S);
  float* esc = (float*)(ws + WS_ESC);
  float* wsq = (float*)(ws + WS_WSQ);
  u16* wt    = (u16*)(ws + WS_WT);
  u16* xs    = (u16*)(ws + WS_XS);
  u16* zbuf  = (u16*)(ws + WS_Z);

  k_pre1<<<2080, 256, 0, stream>>>(style, mw, mb, weight, s, wsq, (u64*)zbuf);
  k_pre2<<<6144, 256, 0, stream>>>(wsq, s, weight, x, esc, wt, xs);
  k_conv<<<dim3(2, 128), 512, 0, stream>>>(wt, xs, zbuf, esc, noise, nw, ab, out);
}